// Round 1
// 612.809 us; speedup vs baseline: 1.4759x; 1.4759x over previous
//
#include <hip/hip_runtime.h>

typedef unsigned short u16;
typedef float f32x4 __attribute__((ext_vector_type(4)));
typedef short s16x8 __attribute__((ext_vector_type(8)));
typedef _Float16 f16x8 __attribute__((ext_vector_type(8)));

static __device__ __forceinline__ u16 f2h(float f) {
  return __builtin_bit_cast(u16, (_Float16)f);   // RNE
}

static __device__ __forceinline__ f32x4 MFMA(s16x8 a, s16x8 b, f32x4 c) {
  return __builtin_amdgcn_mfma_f32_16x16x32_f16(
      __builtin_bit_cast(f16x8, a), __builtin_bit_cast(f16x8, b), c, 0, 0, 0);
}

// ============================================================================
// K0: convert pointwise weights fp32 -> fp16 (768*1024 elems). 768 blocks.
// ============================================================================
__global__ __launch_bounds__(256) void convw_kernel(
    const float* __restrict__ w, u16* __restrict__ wb) {
  const int i = (blockIdx.x * 256 + threadIdx.x) * 4;
  const f32x4 v = *(const f32x4*)(w + i);
  ushort4 o;
  o.x = f2h(v.x); o.y = f2h(v.y); o.z = f2h(v.z); o.w = f2h(v.w);
  *(ushort4*)(wb + i) = o;
}

// ============================================================================
// K1 (rewritten): depthwise 3x3 + bias on concat(x,y); out Tt[b][p][ic] fp16.
// Latency-bound before (9 shifted dword re-loads + 10 broadcast weight loads
// per channel-row -> VALUBusy 15%, HBM 7.7%). Now: float4 row loads (1 instr
// per 64-float row per 16-lane group), horizontal taps via register shifts +
// 2 shuffles/row, 4 output rows per block (6 rows loaded -> 1.5x read
// redundancy instead of 3x), weights staged in LDS, 8B/lane output stores.
// grid (icb=16, hb=16, b=16), 256 threads.
// ============================================================================
__global__ __launch_bounds__(256, 4) void dwconv_kernel(
    const float* __restrict__ x, const float* __restrict__ y,
    const float* __restrict__ dww, const float* __restrict__ dwb,
    u16* __restrict__ Tt) {
  __shared__ __align__(16) u16 tile[4][64][68];  // [ro][ch][w], pad 68 (136B rows, 8B-aligned)
  __shared__ float wl[640];                      // 64ch x 9 weights + 64 bias
  const int icb = blockIdx.x, hb = blockIdx.y, b = blockIdx.z;
  const int t = threadIdx.x;

  // stage weights+bias once (kills the per-thread broadcast vector loads)
  for (int i = t; i < 576; i += 256) wl[i] = dww[icb * 576 + i];
  if (t < 64) wl[576 + t] = dwb[icb * 64 + t];
  __syncthreads();

  const int wq = t & 15;   // w-quad: covers w = wq*4 .. wq*4+3
  const int cs = t >> 4;   // 0..15
  const int h0 = hb * 4;

#pragma unroll
  for (int cc = 0; cc < 4; ++cc) {
    const int ch = cs * 4 + cc;                  // 0..63
    const int ic = icb * 64 + ch;
    const float* src = (ic < 512) ? (x + (size_t)(b * 512 + ic) * 4096)
                                  : (y + (size_t)(b * 512 + (ic - 512)) * 4096);
    // load 6 input rows (h0-1 .. h0+4) as float4; halo via shfl
    f32x4 r[6];
    float lm[6], lp[6];
#pragma unroll
    for (int j = 0; j < 6; ++j) {
      const int hh = h0 - 1 + j;
      f32x4 v = {0.f, 0.f, 0.f, 0.f};
      if (hh >= 0 && hh <= 63) v = *(const f32x4*)(src + hh * 64 + wq * 4);
      r[j] = v;
      const float l = __shfl_up(v.w, 1, 16);     // prev quad's last elem
      const float rr = __shfl_down(v.x, 1, 16);  // next quad's first elem
      lm[j] = (wq == 0) ? 0.f : l;
      lp[j] = (wq == 15) ? 0.f : rr;
    }
    const float w00 = wl[ch * 9 + 0], w01 = wl[ch * 9 + 1], w02 = wl[ch * 9 + 2];
    const float w10 = wl[ch * 9 + 3], w11 = wl[ch * 9 + 4], w12 = wl[ch * 9 + 5];
    const float w20 = wl[ch * 9 + 6], w21 = wl[ch * 9 + 7], w22 = wl[ch * 9 + 8];
    const float bias = wl[576 + ch];
#pragma unroll
    for (int ro = 0; ro < 4; ++ro) {
      f32x4 acc = {bias, bias, bias, bias};
#pragma unroll
      for (int d = 0; d < 3; ++d) {
        const int j = ro + d;
        const float wa = (d == 0) ? w00 : (d == 1) ? w10 : w20;
        const float wb_ = (d == 0) ? w01 : (d == 1) ? w11 : w21;
        const float wc = (d == 0) ? w02 : (d == 1) ? w12 : w22;
        acc.x += wa * lm[j]   + wb_ * r[j].x + wc * r[j].y;
        acc.y += wa * r[j].x  + wb_ * r[j].y + wc * r[j].z;
        acc.z += wa * r[j].y  + wb_ * r[j].z + wc * r[j].w;
        acc.w += wa * r[j].z  + wb_ * r[j].w + wc * lp[j];
      }
      ushort4 o;
      o.x = f2h(acc.x); o.y = f2h(acc.y); o.z = f2h(acc.z); o.w = f2h(acc.w);
      *(ushort4*)&tile[ro][ch][wq * 4] = o;      // 8B write, 128B/16-lane group
    }
  }
  __syncthreads();

  // transpose out: Tt[b][p][ic], p=(h0+ro)*64+w; 8B/lane, 128B contiguous per
  // 16-lane group (4 ic per lane)
  const int icq = t & 15;
  const size_t outb = (size_t)b * 4096 * 1024 + (size_t)icb * 64 + icq * 4;
#pragma unroll
  for (int it = 0; it < 16; ++it) {
    const int ro = it >> 2;
    const int w = (it & 3) * 16 + (t >> 4);
    ushort4 o;
    o.x = tile[ro][icq * 4 + 0][w];
    o.y = tile[ro][icq * 4 + 1][w];
    o.z = tile[ro][icq * 4 + 2][w];
    o.w = tile[ro][icq * 4 + 3][w];
    const size_t p = (size_t)(h0 + ro) * 64 + w;
    *(ushort4*)(Tt + outb + p * 1024) = o;
  }
}

// ============================================================================
// K2: pointwise 1x1 as NT-GEMM: FM[b][oc][p] = sum_ic W[oc][ic]*Tt[b][p][ic]+bias
// 128x128 tile, BK=64, 4 waves of 64x64, mfma 16x16x32 f16.
// grid (n=32, m=6, b=16), 256 threads
// ============================================================================
__global__ __launch_bounds__(256) void pwgemm_kernel(
    const u16* __restrict__ W, const float* __restrict__ pwb,
    const u16* __restrict__ Tt, u16* __restrict__ FM) {
  __shared__ __align__(16) u16 sA[128 * 64];
  __shared__ __align__(16) u16 sB[128 * 64];
  const int b = blockIdx.z;
  const int m0 = blockIdx.y * 128, n0 = blockIdx.x * 128;
  const int t = threadIdx.x, wv = t >> 6, lane = t & 63;
  const int mw = (wv >> 1) * 64, nw = (wv & 1) * 64;
  const int l15 = lane & 15, lq = lane >> 4;
  f32x4 acc[4][4] = {};
  const u16* Wb = W + (size_t)m0 * 1024;
  const u16* Tb = Tt + ((size_t)b * 4096 + n0) * 1024;
  for (int k0 = 0; k0 < 1024; k0 += 64) {
    s16x8 av[4], bv[4];
#pragma unroll
    for (int jj = 0; jj < 4; ++jj) {
      const int c = jj * 256 + t;           // chunk id, 1024 total
      const int row = c >> 3, col = (c & 7) * 8;
      av[jj] = *(const s16x8*)(Wb + (size_t)row * 1024 + k0 + col);
      bv[jj] = *(const s16x8*)(Tb + (size_t)row * 1024 + k0 + col);
    }
    __syncthreads();   // WAR: previous tile's reads complete
#pragma unroll
    for (int jj = 0; jj < 4; ++jj) {
      const int c = jj * 256 + t;
      const int row = c >> 3, col = (c & 7) * 8;
      *(s16x8*)&sA[row * 64 + col] = av[jj];
      *(s16x8*)&sB[row * 64 + col] = bv[jj];
    }
    __syncthreads();   // RAW: tile visible
#pragma unroll
    for (int ks = 0; ks < 2; ++ks) {
      s16x8 af[4], bfv[4];
#pragma unroll
      for (int i = 0; i < 4; ++i)
        af[i] = *(const s16x8*)&sA[(mw + i * 16 + l15) * 64 + ks * 32 + lq * 8];
#pragma unroll
      for (int j = 0; j < 4; ++j)
        bfv[j] = *(const s16x8*)&sB[(nw + j * 16 + l15) * 64 + ks * 32 + lq * 8];
#pragma unroll
      for (int i = 0; i < 4; ++i)
#pragma unroll
        for (int j = 0; j < 4; ++j)
          acc[i][j] = MFMA(af[i], bfv[j], acc[i][j]);
    }
  }
#pragma unroll
  for (int i = 0; i < 4; ++i)
#pragma unroll
    for (int r = 0; r < 4; ++r) {
      const int oc = m0 + mw + i * 16 + lq * 4 + r;
      const float bias = pwb[oc];
#pragma unroll
      for (int j = 0; j < 4; ++j) {
        const int p = n0 + nw + j * 16 + l15;
        FM[((size_t)b * 768 + oc) * 4096 + p] = f2h(acc[i][j][r] + bias);
      }
    }
}

// ============================================================================
// K3: attention per (b, h, strip of 64 Q rows). Waves split S by ROWS:
// wave wv owns Q rows [wv*16, wv*16+16) x all 256 cols -> softmax is fully
// wave-local. Output fp32. grid (strip=4, h=64, b=16), 256 threads.
// ============================================================================
__global__ __launch_bounds__(256) void attn_kernel(
    const u16* __restrict__ FM, float* __restrict__ out) {
  __shared__ __align__(16) u16 sKV[16384];  // K[256][64]; later VT[64][256]
  __shared__ __align__(16) u16 sP[16384];   // P[64][256]
  const int sb = blockIdx.x, h = blockIdx.y, b = blockIdx.z;
  const int t = threadIdx.x, wv = t >> 6, lane = t & 63;
  const int l15 = lane & 15, lq = lane >> 4;
  const u16* fmb = FM + (size_t)b * 768 * 4096;
  const int hofs = h * 64;

  // stage K[256][64] (channels 256..511): explicit loads + b128 LDS stores
#pragma unroll
  for (int it = 0; it < 8; ++it) {
    const int c = it * 256 + t;            // 2048 chunks of 8 u16
    const int d = c >> 3, w0 = (c & 7) * 8;
    const s16x8 kv = *(const s16x8*)(fmb + (size_t)(256 + d) * 4096 + hofs + w0);
    *(s16x8*)&sKV[d * 64 + w0] = kv;
  }
  // Q fragments for this wave's 16 rows (A layout: m=l15, k contiguous)
  const int qrow = sb * 64 + wv * 16 + l15;
  s16x8 qf[2];
#pragma unroll
  for (int ks = 0; ks < 2; ++ks)
    qf[ks] = *(const s16x8*)(fmb + (size_t)qrow * 4096 + hofs + ks * 32 + lq * 8);
  __syncthreads();

  // S[m][d]: m in wave's 16 rows, d = 0..255 across 16 j-blocks
  f32x4 sreg[16] = {};
#pragma unroll
  for (int ks = 0; ks < 2; ++ks)
#pragma unroll
    for (int j = 0; j < 16; ++j) {
      const s16x8 kf =
          *(const s16x8*)&sKV[(j * 16 + l15) * 64 + ks * 32 + lq * 8];
      sreg[j] = MFMA(qf[ks], kf, sreg[j]);
    }

  // wave-local softmax over d. Row m_local = lq*4 + r; cols = j*16 + l15.
  float inv[4], mx[4];
#pragma unroll
  for (int r = 0; r < 4; ++r) {
    float v = -3.4e38f;
#pragma unroll
    for (int j = 0; j < 16; ++j) v = fmaxf(v, sreg[j][r]);
#pragma unroll
    for (int mk = 1; mk < 16; mk <<= 1) v = fmaxf(v, __shfl_xor(v, mk, 64));
    mx[r] = v;
  }
#pragma unroll
  for (int r = 0; r < 4; ++r) {
    float ss = 0.f;
#pragma unroll
    for (int j = 0; j < 16; ++j) {
      const float e = __expf(fminf(sreg[j][r] - mx[r], 0.f));
      sreg[j][r] = e;
      ss += e;
    }
#pragma unroll
    for (int mk = 1; mk < 16; mk <<= 1) ss += __shfl_xor(ss, mk, 64);
    inv[r] = 1.0f / fmaxf(ss, 1e-30f);
  }
  // P -> sP[row][col] (row-major, k=col contiguous for PV A-fragments)
#pragma unroll
  for (int r = 0; r < 4; ++r) {
    const int row = wv * 16 + lq * 4 + r;
#pragma unroll
    for (int j = 0; j < 16; ++j)
      sP[row * 256 + j * 16 + l15] = f2h(sreg[j][r] * inv[r]);
  }
  __syncthreads();   // all QK reads of sKV done; P visible

  // stage V^T into sKV: VT[w][d] (channels 512..767)
#pragma unroll
  for (int it = 0; it < 8; ++it) {
    const int c = it * 256 + t;
    const int d = c >> 3, w0 = (c & 7) * 8;
    const s16x8 vv = *(const s16x8*)(fmb + (size_t)(512 + d) * 4096 + hofs + w0);
#pragma unroll
    for (int j = 0; j < 8; ++j) sKV[(w0 + j) * 256 + d] = (u16)vv[j];
  }
  __syncthreads();

  // O[m][w] = sum_d P[m][d] V[d][w]; wave's 16 rows, full K=256
  f32x4 o[4] = {};
#pragma unroll
  for (int kk = 0; kk < 8; ++kk) {
    const s16x8 pf = *(const s16x8*)&sP[(wv * 16 + l15) * 256 + kk * 32 + lq * 8];
#pragma unroll
    for (int j = 0; j < 4; ++j) {
      const s16x8 vf = *(const s16x8*)&sKV[(j * 16 + l15) * 256 + kk * 32 + lq * 8];
      o[j] = MFMA(pf, vf, o[j]);
    }
  }
  // out flat = [b][h][c][w], fp32
  const size_t ob = (((size_t)b * 64 + h) * 256 + sb * 64 + wv * 16) * 64;
#pragma unroll
  for (int j = 0; j < 4; ++j)
#pragma unroll
    for (int r = 0; r < 4; ++r)
      out[ob + (size_t)(lq * 4 + r) * 64 + j * 16 + l15] = o[j][r];
}

extern "C" void kernel_launch(void* const* d_in, const int* in_sizes, int n_in,
                              void* d_out, int out_size, void* d_ws, size_t ws_size,
                              hipStream_t stream) {
  (void)in_sizes; (void)n_in; (void)out_size; (void)ws_size;
  const float* x   = (const float*)d_in[0];
  const float* y   = (const float*)d_in[1];
  const float* dww = (const float*)d_in[2];
  const float* dwb = (const float*)d_in[3];
  const float* pww = (const float*)d_in[4];
  const float* pwb = (const float*)d_in[5];
  u16* Tt   = (u16*)d_ws;                        // [16][4096][1024] f16 = 128 MiB
  u16* FM   = Tt + (size_t)16 * 4096 * 1024;     // [16][768][4096]  f16 =  96 MiB
  u16* Wb16 = FM + (size_t)16 * 768 * 4096;      // [768][1024]      f16 = 1.5 MiB
  float* out = (float*)d_out;

  convw_kernel<<<dim3(768), 256, 0, stream>>>(pww, Wb16);
  dwconv_kernel<<<dim3(16, 16, 16), 256, 0, stream>>>(x, y, dww, dwb, Tt);
  pwgemm_kernel<<<dim3(32, 6, 16), 256, 0, stream>>>(Wb16, pwb, Tt, FM);
  attn_kernel<<<dim3(4, 64, 16), 256, 0, stream>>>(FM, out);
}

// Round 2
// 556.389 us; speedup vs baseline: 1.6255x; 1.1014x over previous
//
#include <hip/hip_runtime.h>

typedef unsigned short u16;
typedef float f32x4 __attribute__((ext_vector_type(4)));
typedef short s16x8 __attribute__((ext_vector_type(8)));
typedef _Float16 f16x8 __attribute__((ext_vector_type(8)));

static __device__ __forceinline__ u16 f2h(float f) {
  return __builtin_bit_cast(u16, (_Float16)f);   // RNE
}

static __device__ __forceinline__ f32x4 MFMA(s16x8 a, s16x8 b, f32x4 c) {
  return __builtin_amdgcn_mfma_f32_16x16x32_f16(
      __builtin_bit_cast(f16x8, a), __builtin_bit_cast(f16x8, b), c, 0, 0, 0);
}

// ============================================================================
// K0: convert pointwise weights fp32 -> fp16 (768*1024 elems). 768 blocks.
// ============================================================================
__global__ __launch_bounds__(256) void convw_kernel(
    const float* __restrict__ w, u16* __restrict__ wb) {
  const int i = (blockIdx.x * 256 + threadIdx.x) * 4;
  const f32x4 v = *(const f32x4*)(w + i);
  ushort4 o;
  o.x = f2h(v.x); o.y = f2h(v.y); o.z = f2h(v.z); o.w = f2h(v.w);
  *(ushort4*)(wb + i) = o;
}

// ============================================================================
// K1: depthwise 3x3 + bias on concat(x,y); out Tt[b][p][ic] fp16.
// float4 row loads, halo via shfl, 4 output rows/block, weights in LDS,
// 8B/lane transposed stores. grid (icb=16, hb=16, b=16), 256 threads.
// ============================================================================
__global__ __launch_bounds__(256, 4) void dwconv_kernel(
    const float* __restrict__ x, const float* __restrict__ y,
    const float* __restrict__ dww, const float* __restrict__ dwb,
    u16* __restrict__ Tt) {
  __shared__ __align__(16) u16 tile[4][64][68];  // [ro][ch][w], pad 68
  __shared__ float wl[640];                      // 64ch x 9 weights + 64 bias
  const int icb = blockIdx.x, hb = blockIdx.y, b = blockIdx.z;
  const int t = threadIdx.x;

  for (int i = t; i < 576; i += 256) wl[i] = dww[icb * 576 + i];
  if (t < 64) wl[576 + t] = dwb[icb * 64 + t];
  __syncthreads();

  const int wq = t & 15;   // w-quad: covers w = wq*4 .. wq*4+3
  const int cs = t >> 4;   // 0..15
  const int h0 = hb * 4;

#pragma unroll
  for (int cc = 0; cc < 4; ++cc) {
    const int ch = cs * 4 + cc;                  // 0..63
    const int ic = icb * 64 + ch;
    const float* src = (ic < 512) ? (x + (size_t)(b * 512 + ic) * 4096)
                                  : (y + (size_t)(b * 512 + (ic - 512)) * 4096);
    f32x4 r[6];
    float lm[6], lp[6];
#pragma unroll
    for (int j = 0; j < 6; ++j) {
      const int hh = h0 - 1 + j;
      f32x4 v = {0.f, 0.f, 0.f, 0.f};
      if (hh >= 0 && hh <= 63) v = *(const f32x4*)(src + hh * 64 + wq * 4);
      r[j] = v;
      const float l = __shfl_up(v.w, 1, 16);
      const float rr = __shfl_down(v.x, 1, 16);
      lm[j] = (wq == 0) ? 0.f : l;
      lp[j] = (wq == 15) ? 0.f : rr;
    }
    const float w00 = wl[ch * 9 + 0], w01 = wl[ch * 9 + 1], w02 = wl[ch * 9 + 2];
    const float w10 = wl[ch * 9 + 3], w11 = wl[ch * 9 + 4], w12 = wl[ch * 9 + 5];
    const float w20 = wl[ch * 9 + 6], w21 = wl[ch * 9 + 7], w22 = wl[ch * 9 + 8];
    const float bias = wl[576 + ch];
#pragma unroll
    for (int ro = 0; ro < 4; ++ro) {
      f32x4 acc = {bias, bias, bias, bias};
#pragma unroll
      for (int d = 0; d < 3; ++d) {
        const int j = ro + d;
        const float wa = (d == 0) ? w00 : (d == 1) ? w10 : w20;
        const float wb_ = (d == 0) ? w01 : (d == 1) ? w11 : w21;
        const float wc = (d == 0) ? w02 : (d == 1) ? w12 : w22;
        acc.x += wa * lm[j]   + wb_ * r[j].x + wc * r[j].y;
        acc.y += wa * r[j].x  + wb_ * r[j].y + wc * r[j].z;
        acc.z += wa * r[j].y  + wb_ * r[j].z + wc * r[j].w;
        acc.w += wa * r[j].z  + wb_ * r[j].w + wc * lp[j];
      }
      ushort4 o;
      o.x = f2h(acc.x); o.y = f2h(acc.y); o.z = f2h(acc.z); o.w = f2h(acc.w);
      *(ushort4*)&tile[ro][ch][wq * 4] = o;
    }
  }
  __syncthreads();

  const int icq = t & 15;
  const size_t outb = (size_t)b * 4096 * 1024 + (size_t)icb * 64 + icq * 4;
#pragma unroll
  for (int it = 0; it < 16; ++it) {
    const int ro = it >> 2;
    const int w = (it & 3) * 16 + (t >> 4);
    ushort4 o;
    o.x = tile[ro][icq * 4 + 0][w];
    o.y = tile[ro][icq * 4 + 1][w];
    o.z = tile[ro][icq * 4 + 2][w];
    o.w = tile[ro][icq * 4 + 3][w];
    const size_t p = (size_t)(h0 + ro) * 64 + w;
    *(ushort4*)(Tt + outb + p * 1024) = o;
  }
}

// ============================================================================
// K2: pointwise 1x1 as NT-GEMM: FM[b][oc][p] = sum_ic W[oc][ic]*Tt[b][p][ic]+bias
// 128x128 tile, BK=64, 4 waves of 64x64, mfma 16x16x32 f16.
// T2 XOR-swizzle on sA/sB: row stride is 128B -> unswizzled fragment reads are
// ~16-way bank conflicts (3.8e7 conflict cycles/dispatch = 36% of time).
// Store (row, col) at col ^ ((row&7)<<3); cols are 8-u16 aligned so b128
// accesses stay contiguous. grid (n=32, m=6, b=16), 256 threads.
// ============================================================================
__global__ __launch_bounds__(256) void pwgemm_kernel(
    const u16* __restrict__ W, const float* __restrict__ pwb,
    const u16* __restrict__ Tt, u16* __restrict__ FM) {
  __shared__ __align__(16) u16 sA[128 * 64];
  __shared__ __align__(16) u16 sB[128 * 64];
  const int b = blockIdx.z;
  const int m0 = blockIdx.y * 128, n0 = blockIdx.x * 128;
  const int t = threadIdx.x, wv = t >> 6, lane = t & 63;
  const int mw = (wv >> 1) * 64, nw = (wv & 1) * 64;
  const int l15 = lane & 15, lq = lane >> 4;
  const int rsw = (l15 & 7) << 3;           // read-side swizzle (row&7 == l15&7)
  f32x4 acc[4][4] = {};
  const u16* Wb = W + (size_t)m0 * 1024;
  const u16* Tb = Tt + ((size_t)b * 4096 + n0) * 1024;
  for (int k0 = 0; k0 < 1024; k0 += 64) {
    s16x8 av[4], bv[4];
#pragma unroll
    for (int jj = 0; jj < 4; ++jj) {
      const int c = jj * 256 + t;           // chunk id, 1024 total
      const int row = c >> 3, col = (c & 7) * 8;
      av[jj] = *(const s16x8*)(Wb + (size_t)row * 1024 + k0 + col);
      bv[jj] = *(const s16x8*)(Tb + (size_t)row * 1024 + k0 + col);
    }
    __syncthreads();   // WAR: previous tile's reads complete
#pragma unroll
    for (int jj = 0; jj < 4; ++jj) {
      const int c = jj * 256 + t;
      const int row = c >> 3, col = (c & 7) * 8;
      const int sc = col ^ ((row & 7) << 3);   // swizzled column
      *(s16x8*)&sA[row * 64 + sc] = av[jj];
      *(s16x8*)&sB[row * 64 + sc] = bv[jj];
    }
    __syncthreads();   // RAW: tile visible
#pragma unroll
    for (int ks = 0; ks < 2; ++ks) {
      s16x8 af[4], bfv[4];
      const int cbase = (ks * 32 + lq * 8) ^ rsw;
#pragma unroll
      for (int i = 0; i < 4; ++i)
        af[i] = *(const s16x8*)&sA[(mw + i * 16 + l15) * 64 + cbase];
#pragma unroll
      for (int j = 0; j < 4; ++j)
        bfv[j] = *(const s16x8*)&sB[(nw + j * 16 + l15) * 64 + cbase];
#pragma unroll
      for (int i = 0; i < 4; ++i)
#pragma unroll
        for (int j = 0; j < 4; ++j)
          acc[i][j] = MFMA(af[i], bfv[j], acc[i][j]);
    }
  }
#pragma unroll
  for (int i = 0; i < 4; ++i)
#pragma unroll
    for (int r = 0; r < 4; ++r) {
      const int oc = m0 + mw + i * 16 + lq * 4 + r;
      const float bias = pwb[oc];
#pragma unroll
      for (int j = 0; j < 4; ++j) {
        const int p = n0 + nw + j * 16 + l15;
        FM[((size_t)b * 768 + oc) * 4096 + p] = f2h(acc[i][j][r] + bias);
      }
    }
}

// ============================================================================
// K3: attention per (b, h, strip of 64 Q rows). Waves split S by ROWS ->
// softmax fully wave-local. Same T2 XOR swizzle on all three LDS tiles
// (K rows = 128B stride, P/VT rows = 512B stride: both were 16-way read
// conflicts unswizzled). grid (strip=4, h=64, b=16), 256 threads.
// ============================================================================
__global__ __launch_bounds__(256) void attn_kernel(
    const u16* __restrict__ FM, float* __restrict__ out) {
  __shared__ __align__(16) u16 sKV[16384];  // K[256][64]; later VT[64][256]
  __shared__ __align__(16) u16 sP[16384];   // P[64][256]
  const int sb = blockIdx.x, h = blockIdx.y, b = blockIdx.z;
  const int t = threadIdx.x, wv = t >> 6, lane = t & 63;
  const int l15 = lane & 15, lq = lane >> 4;
  const int rsw = (l15 & 7) << 3;           // read-side swizzle
  const u16* fmb = FM + (size_t)b * 768 * 4096;
  const int hofs = h * 64;

  // stage K[256][64] (channels 256..511), swizzled
#pragma unroll
  for (int it = 0; it < 8; ++it) {
    const int c = it * 256 + t;            // 2048 chunks of 8 u16
    const int d = c >> 3, w0 = (c & 7) * 8;
    const s16x8 kv = *(const s16x8*)(fmb + (size_t)(256 + d) * 4096 + hofs + w0);
    *(s16x8*)&sKV[d * 64 + (w0 ^ ((d & 7) << 3))] = kv;
  }
  // Q fragments for this wave's 16 rows (A layout: m=l15, k contiguous)
  const int qrow = sb * 64 + wv * 16 + l15;
  s16x8 qf[2];
#pragma unroll
  for (int ks = 0; ks < 2; ++ks)
    qf[ks] = *(const s16x8*)(fmb + (size_t)qrow * 4096 + hofs + ks * 32 + lq * 8);
  __syncthreads();

  // S[m][d]: m in wave's 16 rows, d = 0..255 across 16 j-blocks
  f32x4 sreg[16] = {};
#pragma unroll
  for (int ks = 0; ks < 2; ++ks) {
    const int cbase = (ks * 32 + lq * 8) ^ rsw;
#pragma unroll
    for (int j = 0; j < 16; ++j) {
      const s16x8 kf = *(const s16x8*)&sKV[(j * 16 + l15) * 64 + cbase];
      sreg[j] = MFMA(qf[ks], kf, sreg[j]);
    }
  }

  // wave-local softmax over d. Row m_local = lq*4 + r; cols = j*16 + l15.
  float inv[4], mx[4];
#pragma unroll
  for (int r = 0; r < 4; ++r) {
    float v = -3.4e38f;
#pragma unroll
    for (int j = 0; j < 16; ++j) v = fmaxf(v, sreg[j][r]);
#pragma unroll
    for (int mk = 1; mk < 16; mk <<= 1) v = fmaxf(v, __shfl_xor(v, mk, 64));
    mx[r] = v;
  }
#pragma unroll
  for (int r = 0; r < 4; ++r) {
    float ss = 0.f;
#pragma unroll
    for (int j = 0; j < 16; ++j) {
      const float e = __expf(fminf(sreg[j][r] - mx[r], 0.f));
      sreg[j][r] = e;
      ss += e;
    }
#pragma unroll
    for (int mk = 1; mk < 16; mk <<= 1) ss += __shfl_xor(ss, mk, 64);
    inv[r] = 1.0f / fmaxf(ss, 1e-30f);
  }
  // P -> sP[row][col ^ ((row&7)<<3)]
#pragma unroll
  for (int r = 0; r < 4; ++r) {
    const int row = wv * 16 + lq * 4 + r;
    const int s = (row & 7) << 3;
#pragma unroll
    for (int j = 0; j < 16; ++j)
      sP[row * 256 + ((j * 16 + l15) ^ s)] = f2h(sreg[j][r] * inv[r]);
  }
  __syncthreads();   // all QK reads of sKV done; P visible

  // stage V^T into sKV: VT[w][d] (channels 512..767), swizzled
#pragma unroll
  for (int it = 0; it < 8; ++it) {
    const int c = it * 256 + t;
    const int d = c >> 3, w0 = (c & 7) * 8;
    const s16x8 vv = *(const s16x8*)(fmb + (size_t)(512 + d) * 4096 + hofs + w0);
#pragma unroll
    for (int j = 0; j < 8; ++j) {
      const int rr = w0 + j;
      sKV[rr * 256 + (d ^ ((rr & 7) << 3))] = (u16)vv[j];
    }
  }
  __syncthreads();

  // O[m][w] = sum_d P[m][d] V[d][w]; wave's 16 rows, full K=256
  f32x4 o[4] = {};
#pragma unroll
  for (int kk = 0; kk < 8; ++kk) {
    const int cbase = (kk * 32 + lq * 8) ^ rsw;
    const s16x8 pf = *(const s16x8*)&sP[(wv * 16 + l15) * 256 + cbase];
#pragma unroll
    for (int j = 0; j < 4; ++j) {
      const s16x8 vf = *(const s16x8*)&sKV[(j * 16 + l15) * 256 + cbase];
      o[j] = MFMA(pf, vf, o[j]);
    }
  }
  // out flat = [b][h][c][w], fp32
  const size_t ob = (((size_t)b * 64 + h) * 256 + sb * 64 + wv * 16) * 64;
#pragma unroll
  for (int j = 0; j < 4; ++j)
#pragma unroll
    for (int r = 0; r < 4; ++r)
      out[ob + (size_t)(lq * 4 + r) * 64 + j * 16 + l15] = o[j][r];
}

extern "C" void kernel_launch(void* const* d_in, const int* in_sizes, int n_in,
                              void* d_out, int out_size, void* d_ws, size_t ws_size,
                              hipStream_t stream) {
  (void)in_sizes; (void)n_in; (void)out_size; (void)ws_size;
  const float* x   = (const float*)d_in[0];
  const float* y   = (const float*)d_in[1];
  const float* dww = (const float*)d_in[2];
  const float* dwb = (const float*)d_in[3];
  const float* pww = (const float*)d_in[4];
  const float* pwb = (const float*)d_in[5];
  u16* Tt   = (u16*)d_ws;                        // [16][4096][1024] f16 = 128 MiB
  u16* FM   = Tt + (size_t)16 * 4096 * 1024;     // [16][768][4096]  f16 =  96 MiB
  u16* Wb16 = FM + (size_t)16 * 768 * 4096;      // [768][1024]      f16 = 1.5 MiB
  float* out = (float*)d_out;

  convw_kernel<<<dim3(768), 256, 0, stream>>>(pww, Wb16);
  dwconv_kernel<<<dim3(16, 16, 16), 256, 0, stream>>>(x, y, dww, dwb, Tt);
  pwgemm_kernel<<<dim3(32, 6, 16), 256, 0, stream>>>(Wb16, pwb, Tt, FM);
  attn_kernel<<<dim3(4, 64, 16), 256, 0, stream>>>(FM, out);
}

// Round 3
// 532.874 us; speedup vs baseline: 1.6973x; 1.0441x over previous
//
#include <hip/hip_runtime.h>

typedef unsigned short u16;
typedef float f32x4 __attribute__((ext_vector_type(4)));
typedef short s16x8 __attribute__((ext_vector_type(8)));
typedef _Float16 f16x8 __attribute__((ext_vector_type(8)));

static __device__ __forceinline__ u16 f2h(float f) {
  return __builtin_bit_cast(u16, (_Float16)f);   // RNE
}

static __device__ __forceinline__ f32x4 MFMA(s16x8 a, s16x8 b, f32x4 c) {
  return __builtin_amdgcn_mfma_f32_16x16x32_f16(
      __builtin_bit_cast(f16x8, a), __builtin_bit_cast(f16x8, b), c, 0, 0, 0);
}

// async global->LDS, 16B per lane. LDS dest = wave-uniform base + lane*16.
static __device__ __forceinline__ void g2l16(const u16* g, u16* l) {
  __builtin_amdgcn_global_load_lds(
      (const __attribute__((address_space(1))) void*)g,
      (__attribute__((address_space(3))) void*)l, 16, 0, 0);
}

// ============================================================================
// K0: convert pointwise weights fp32 -> fp16 (768*1024 elems). 768 blocks.
// ============================================================================
__global__ __launch_bounds__(256) void convw_kernel(
    const float* __restrict__ w, u16* __restrict__ wb) {
  const int i = (blockIdx.x * 256 + threadIdx.x) * 4;
  const f32x4 v = *(const f32x4*)(w + i);
  ushort4 o;
  o.x = f2h(v.x); o.y = f2h(v.y); o.z = f2h(v.z); o.w = f2h(v.w);
  *(ushort4*)(wb + i) = o;
}

// ============================================================================
// K1: depthwise 3x3 + bias on concat(x,y); out Tt[b][p][ic] fp16.
// float4 row loads, halo via shfl, 4 output rows/block, weights in LDS,
// 8B/lane transposed stores. grid (icb=16, hb=16, b=16), 256 threads.
// ============================================================================
__global__ __launch_bounds__(256, 4) void dwconv_kernel(
    const float* __restrict__ x, const float* __restrict__ y,
    const float* __restrict__ dww, const float* __restrict__ dwb,
    u16* __restrict__ Tt) {
  __shared__ __align__(16) u16 tile[4][64][68];  // [ro][ch][w], pad 68
  __shared__ float wl[640];                      // 64ch x 9 weights + 64 bias
  const int icb = blockIdx.x, hb = blockIdx.y, b = blockIdx.z;
  const int t = threadIdx.x;

  for (int i = t; i < 576; i += 256) wl[i] = dww[icb * 576 + i];
  if (t < 64) wl[576 + t] = dwb[icb * 64 + t];
  __syncthreads();

  const int wq = t & 15;   // w-quad: covers w = wq*4 .. wq*4+3
  const int cs = t >> 4;   // 0..15
  const int h0 = hb * 4;

#pragma unroll
  for (int cc = 0; cc < 4; ++cc) {
    const int ch = cs * 4 + cc;                  // 0..63
    const int ic = icb * 64 + ch;
    const float* src = (ic < 512) ? (x + (size_t)(b * 512 + ic) * 4096)
                                  : (y + (size_t)(b * 512 + (ic - 512)) * 4096);
    f32x4 r[6];
    float lm[6], lp[6];
#pragma unroll
    for (int j = 0; j < 6; ++j) {
      const int hh = h0 - 1 + j;
      f32x4 v = {0.f, 0.f, 0.f, 0.f};
      if (hh >= 0 && hh <= 63) v = *(const f32x4*)(src + hh * 64 + wq * 4);
      r[j] = v;
      const float l = __shfl_up(v.w, 1, 16);
      const float rr = __shfl_down(v.x, 1, 16);
      lm[j] = (wq == 0) ? 0.f : l;
      lp[j] = (wq == 15) ? 0.f : rr;
    }
    const float w00 = wl[ch * 9 + 0], w01 = wl[ch * 9 + 1], w02 = wl[ch * 9 + 2];
    const float w10 = wl[ch * 9 + 3], w11 = wl[ch * 9 + 4], w12 = wl[ch * 9 + 5];
    const float w20 = wl[ch * 9 + 6], w21 = wl[ch * 9 + 7], w22 = wl[ch * 9 + 8];
    const float bias = wl[576 + ch];
#pragma unroll
    for (int ro = 0; ro < 4; ++ro) {
      f32x4 acc = {bias, bias, bias, bias};
#pragma unroll
      for (int d = 0; d < 3; ++d) {
        const int j = ro + d;
        const float wa = (d == 0) ? w00 : (d == 1) ? w10 : w20;
        const float wb_ = (d == 0) ? w01 : (d == 1) ? w11 : w21;
        const float wc = (d == 0) ? w02 : (d == 1) ? w12 : w22;
        acc.x += wa * lm[j]   + wb_ * r[j].x + wc * r[j].y;
        acc.y += wa * r[j].x  + wb_ * r[j].y + wc * r[j].z;
        acc.z += wa * r[j].y  + wb_ * r[j].z + wc * r[j].w;
        acc.w += wa * r[j].z  + wb_ * r[j].w + wc * lp[j];
      }
      ushort4 o;
      o.x = f2h(acc.x); o.y = f2h(acc.y); o.z = f2h(acc.z); o.w = f2h(acc.w);
      *(ushort4*)&tile[ro][ch][wq * 4] = o;
    }
  }
  __syncthreads();

  const int icq = t & 15;
  const size_t outb = (size_t)b * 4096 * 1024 + (size_t)icb * 64 + icq * 4;
#pragma unroll
  for (int it = 0; it < 16; ++it) {
    const int ro = it >> 2;
    const int w = (it & 3) * 16 + (t >> 4);
    ushort4 o;
    o.x = tile[ro][icq * 4 + 0][w];
    o.y = tile[ro][icq * 4 + 1][w];
    o.z = tile[ro][icq * 4 + 2][w];
    o.w = tile[ro][icq * 4 + 3][w];
    const size_t p = (size_t)(h0 + ro) * 64 + w;
    *(ushort4*)(Tt + outb + p * 1024) = o;
  }
}

// ============================================================================
// K2: pointwise 1x1 as NT-GEMM: FM[b][oc][p] = sum_ic W[oc][ic]*Tt[b][p][ic]+bias
// 128x128 tile, BK=64, 4 waves of 64x64, mfma 16x16x32 f16.
// Staging via global_load_lds (16B/lane, direct to LDS): LDS layout stays the
// round-1 swizzled one; linear LDS dest + PRE-SWIZZLED global source column
// 8*((lane&7)^(lane>>3)) reproduces it (rule #21: inverse-swz source + swz read).
// grid (n=32, m=6, b=16), 256 threads.
// ============================================================================
__global__ __launch_bounds__(256) void pwgemm_kernel(
    const u16* __restrict__ W, const float* __restrict__ pwb,
    const u16* __restrict__ Tt, u16* __restrict__ FM) {
  __shared__ __align__(16) u16 sA[128 * 64];
  __shared__ __align__(16) u16 sB[128 * 64];
  const int b = blockIdx.z;
  const int m0 = blockIdx.y * 128, n0 = blockIdx.x * 128;
  const int t = threadIdx.x, wv = t >> 6, lane = t & 63;
  const int mw = (wv >> 1) * 64, nw = (wv & 1) * 64;
  const int l15 = lane & 15, lq = lane >> 4;
  const int rsw = (l15 & 7) << 3;           // read-side swizzle (row&7 == l15&7)
  f32x4 acc[4][4] = {};
  // pre-swizzled per-lane global source; wave-uniform LDS bases
  const int r8 = lane >> 3;                  // row-within-8 == (row&7)
  const int colsw = 8 * ((lane & 7) ^ r8);   // inverse-swizzled k-column
  const u16* gA = W + ((size_t)m0 + wv * 8 + r8) * 1024 + colsw;
  const u16* gB = Tt + ((size_t)b * 4096 + n0 + wv * 8 + r8) * 1024 + colsw;
  u16* lA = sA + wv * 512;
  u16* lB = sB + wv * 512;
  for (int k0 = 0; k0 < 1024; k0 += 64) {
    __syncthreads();   // WAR: all reads of previous tile done before overwrite
#pragma unroll
    for (int jj = 0; jj < 4; ++jj) {
      g2l16(gA + (size_t)jj * 32 * 1024 + k0, lA + jj * 2048);
      g2l16(gB + (size_t)jj * 32 * 1024 + k0, lB + jj * 2048);
    }
    __syncthreads();   // compiler drains vmcnt(0) before barrier: tile visible
#pragma unroll
    for (int ks = 0; ks < 2; ++ks) {
      s16x8 af[4], bfv[4];
      const int cbase = (ks * 32 + lq * 8) ^ rsw;
#pragma unroll
      for (int i = 0; i < 4; ++i)
        af[i] = *(const s16x8*)&sA[(mw + i * 16 + l15) * 64 + cbase];
#pragma unroll
      for (int j = 0; j < 4; ++j)
        bfv[j] = *(const s16x8*)&sB[(nw + j * 16 + l15) * 64 + cbase];
#pragma unroll
      for (int i = 0; i < 4; ++i)
#pragma unroll
        for (int j = 0; j < 4; ++j)
          acc[i][j] = MFMA(af[i], bfv[j], acc[i][j]);
    }
  }
#pragma unroll
  for (int i = 0; i < 4; ++i)
#pragma unroll
    for (int r = 0; r < 4; ++r) {
      const int oc = m0 + mw + i * 16 + lq * 4 + r;
      const float bias = pwb[oc];
#pragma unroll
      for (int j = 0; j < 4; ++j) {
        const int p = n0 + nw + j * 16 + l15;
        FM[((size_t)b * 768 + oc) * 4096 + p] = f2h(acc[i][j][r] + bias);
      }
    }
}

// ============================================================================
// K3: attention per (b, h, strip of 64 Q rows). Waves split S by ROWS ->
// softmax fully wave-local. K staged via global_load_lds (pre-swizzled source,
// same trick as K2). V^T swizzle upgraded to ((rr&7)^((rr>>3)&7))<<3: the old
// (rr&7)<<3 fixed reads but left the scalar WRITES 8-way conflicted (8 lanes
// sharing d write rows 2048 u16 apart -> same bank). New form spreads both
// sides to <=2-way. grid (strip=4, h=64, b=16), 256 threads.
// ============================================================================
__global__ __launch_bounds__(256) void attn_kernel(
    const u16* __restrict__ FM, float* __restrict__ out) {
  __shared__ __align__(16) u16 sKV[16384];  // K[256][64]; later VT[64][256]
  __shared__ __align__(16) u16 sP[16384];   // P[64][256]
  const int sb = blockIdx.x, h = blockIdx.y, b = blockIdx.z;
  const int t = threadIdx.x, wv = t >> 6, lane = t & 63;
  const int l15 = lane & 15, lq = lane >> 4;
  const int rsw = (l15 & 7) << 3;           // read-side swizzle (K, P tiles)
  const u16* fmb = FM + (size_t)b * 768 * 4096;
  const int hofs = h * 64;

  // stage K[256][64] (channels 256..511) via global_load_lds, swizzled layout
  const int r8 = lane >> 3;
  const int colsw = 8 * ((lane & 7) ^ r8);
  const u16* gK = fmb + ((size_t)(256 + wv * 8 + r8)) * 4096 + hofs + colsw;
  u16* lK = sKV + wv * 512;
#pragma unroll
  for (int it = 0; it < 8; ++it)
    g2l16(gK + (size_t)it * 32 * 4096, lK + it * 2048);

  // Q fragments for this wave's 16 rows (A layout: m=l15, k contiguous)
  const int qrow = sb * 64 + wv * 16 + l15;
  s16x8 qf[2];
#pragma unroll
  for (int ks = 0; ks < 2; ++ks)
    qf[ks] = *(const s16x8*)(fmb + (size_t)qrow * 4096 + hofs + ks * 32 + lq * 8);
  __syncthreads();   // vmcnt(0) drained before barrier: K tile visible

  // S[m][d]: m in wave's 16 rows, d = 0..255 across 16 j-blocks
  f32x4 sreg[16] = {};
#pragma unroll
  for (int ks = 0; ks < 2; ++ks) {
    const int cbase = (ks * 32 + lq * 8) ^ rsw;
#pragma unroll
    for (int j = 0; j < 16; ++j) {
      const s16x8 kf = *(const s16x8*)&sKV[(j * 16 + l15) * 64 + cbase];
      sreg[j] = MFMA(qf[ks], kf, sreg[j]);
    }
  }

  // wave-local softmax over d. Row m_local = lq*4 + r; cols = j*16 + l15.
  float inv[4], mx[4];
#pragma unroll
  for (int r = 0; r < 4; ++r) {
    float v = -3.4e38f;
#pragma unroll
    for (int j = 0; j < 16; ++j) v = fmaxf(v, sreg[j][r]);
#pragma unroll
    for (int mk = 1; mk < 16; mk <<= 1) v = fmaxf(v, __shfl_xor(v, mk, 64));
    mx[r] = v;
  }
#pragma unroll
  for (int r = 0; r < 4; ++r) {
    float ss = 0.f;
#pragma unroll
    for (int j = 0; j < 16; ++j) {
      const float e = __expf(fminf(sreg[j][r] - mx[r], 0.f));
      sreg[j][r] = e;
      ss += e;
    }
#pragma unroll
    for (int mk = 1; mk < 16; mk <<= 1) ss += __shfl_xor(ss, mk, 64);
    inv[r] = 1.0f / fmaxf(ss, 1e-30f);
  }
  // P -> sP[row][col ^ ((row&7)<<3)]
#pragma unroll
  for (int r = 0; r < 4; ++r) {
    const int row = wv * 16 + lq * 4 + r;
    const int s = (row & 7) << 3;
#pragma unroll
    for (int j = 0; j < 16; ++j)
      sP[row * 256 + ((j * 16 + l15) ^ s)] = f2h(sreg[j][r] * inv[r]);
  }
  __syncthreads();   // all QK reads of sKV done; P visible

  // stage V^T into sKV: VT[w][d] (channels 512..767), write/read-balanced swz
#pragma unroll
  for (int it = 0; it < 8; ++it) {
    const int c = it * 256 + t;
    const int d = c >> 3, w0 = (c & 7) * 8;
    const s16x8 vv = *(const s16x8*)(fmb + (size_t)(512 + d) * 4096 + hofs + w0);
#pragma unroll
    for (int j = 0; j < 8; ++j) {
      const int rr = w0 + j;
      const int s = ((rr & 7) ^ ((rr >> 3) & 7)) << 3;
      sKV[rr * 256 + (d ^ s)] = (u16)vv[j];
    }
  }
  __syncthreads();

  // O[m][w] = sum_d P[m][d] V[d][w]; wave's 16 rows, full K=256
  f32x4 o[4] = {};
#pragma unroll
  for (int kk = 0; kk < 8; ++kk) {
    const int cbase = kk * 32 + lq * 8;
    const s16x8 pf = *(const s16x8*)&sP[(wv * 16 + l15) * 256 + (cbase ^ rsw)];
#pragma unroll
    for (int j = 0; j < 4; ++j) {
      const int rr = j * 16 + l15;
      const int vsw = ((rr & 7) ^ ((rr >> 3) & 7)) << 3;
      const s16x8 vf = *(const s16x8*)&sKV[rr * 256 + (cbase ^ vsw)];
      o[j] = MFMA(pf, vf, o[j]);
    }
  }
  // out flat = [b][h][c][w], fp32
  const size_t ob = (((size_t)b * 64 + h) * 256 + sb * 64 + wv * 16) * 64;
#pragma unroll
  for (int j = 0; j < 4; ++j)
#pragma unroll
    for (int r = 0; r < 4; ++r)
      out[ob + (size_t)(lq * 4 + r) * 64 + j * 16 + l15] = o[j][r];
}

extern "C" void kernel_launch(void* const* d_in, const int* in_sizes, int n_in,
                              void* d_out, int out_size, void* d_ws, size_t ws_size,
                              hipStream_t stream) {
  (void)in_sizes; (void)n_in; (void)out_size; (void)ws_size;
  const float* x   = (const float*)d_in[0];
  const float* y   = (const float*)d_in[1];
  const float* dww = (const float*)d_in[2];
  const float* dwb = (const float*)d_in[3];
  const float* pww = (const float*)d_in[4];
  const float* pwb = (const float*)d_in[5];
  u16* Tt   = (u16*)d_ws;                        // [16][4096][1024] f16 = 128 MiB
  u16* FM   = Tt + (size_t)16 * 4096 * 1024;     // [16][768][4096]  f16 =  96 MiB
  u16* Wb16 = FM + (size_t)16 * 768 * 4096;      // [768][1024]      f16 = 1.5 MiB
  float* out = (float*)d_out;

  convw_kernel<<<dim3(768), 256, 0, stream>>>(pww, Wb16);
  dwconv_kernel<<<dim3(16, 16, 16), 256, 0, stream>>>(x, y, dww, dwb, Tt);
  pwgemm_kernel<<<dim3(32, 6, 16), 256, 0, stream>>>(Wb16, pwb, Tt, FM);
  attn_kernel<<<dim3(4, 64, 16), 256, 0, stream>>>(FM, out);
}

// Round 4
// 526.740 us; speedup vs baseline: 1.7170x; 1.0116x over previous
//
#include <hip/hip_runtime.h>

typedef unsigned short u16;
typedef float f32x4 __attribute__((ext_vector_type(4)));
typedef short s16x8 __attribute__((ext_vector_type(8)));
typedef _Float16 f16x8 __attribute__((ext_vector_type(8)));

static __device__ __forceinline__ u16 f2h(float f) {
  return __builtin_bit_cast(u16, (_Float16)f);   // RNE
}

static __device__ __forceinline__ f32x4 MFMA(s16x8 a, s16x8 b, f32x4 c) {
  return __builtin_amdgcn_mfma_f32_16x16x32_f16(
      __builtin_bit_cast(f16x8, a), __builtin_bit_cast(f16x8, b), c, 0, 0, 0);
}

// async global->LDS, 16B per lane. LDS dest = wave-uniform base + lane*16.
static __device__ __forceinline__ void g2l16(const u16* g, u16* l) {
  __builtin_amdgcn_global_load_lds(
      (const __attribute__((address_space(1))) void*)g,
      (__attribute__((address_space(3))) void*)l, 16, 0, 0);
}

// ============================================================================
// K0: convert pointwise weights fp32 -> fp16 (768*1024 elems). 768 blocks.
// ============================================================================
__global__ __launch_bounds__(256) void convw_kernel(
    const float* __restrict__ w, u16* __restrict__ wb) {
  const int i = (blockIdx.x * 256 + threadIdx.x) * 4;
  const f32x4 v = *(const f32x4*)(w + i);
  ushort4 o;
  o.x = f2h(v.x); o.y = f2h(v.y); o.z = f2h(v.z); o.w = f2h(v.w);
  *(ushort4*)(wb + i) = o;
}

// ============================================================================
// K1: depthwise 3x3 + bias on concat(x,y); out Tt[b][p][ic] fp16.
// float4 row loads, halo via shfl, 4 output rows/block, weights in LDS,
// 8B/lane transposed stores. grid (icb=16, hb=16, b=16), 256 threads.
// ============================================================================
__global__ __launch_bounds__(256, 4) void dwconv_kernel(
    const float* __restrict__ x, const float* __restrict__ y,
    const float* __restrict__ dww, const float* __restrict__ dwb,
    u16* __restrict__ Tt) {
  __shared__ __align__(16) u16 tile[4][64][68];  // [ro][ch][w], pad 68
  __shared__ float wl[640];                      // 64ch x 9 weights + 64 bias
  const int icb = blockIdx.x, hb = blockIdx.y, b = blockIdx.z;
  const int t = threadIdx.x;

  for (int i = t; i < 576; i += 256) wl[i] = dww[icb * 576 + i];
  if (t < 64) wl[576 + t] = dwb[icb * 64 + t];
  __syncthreads();

  const int wq = t & 15;   // w-quad: covers w = wq*4 .. wq*4+3
  const int cs = t >> 4;   // 0..15
  const int h0 = hb * 4;

#pragma unroll
  for (int cc = 0; cc < 4; ++cc) {
    const int ch = cs * 4 + cc;                  // 0..63
    const int ic = icb * 64 + ch;
    const float* src = (ic < 512) ? (x + (size_t)(b * 512 + ic) * 4096)
                                  : (y + (size_t)(b * 512 + (ic - 512)) * 4096);
    f32x4 r[6];
    float lm[6], lp[6];
#pragma unroll
    for (int j = 0; j < 6; ++j) {
      const int hh = h0 - 1 + j;
      f32x4 v = {0.f, 0.f, 0.f, 0.f};
      if (hh >= 0 && hh <= 63) v = *(const f32x4*)(src + hh * 64 + wq * 4);
      r[j] = v;
      const float l = __shfl_up(v.w, 1, 16);
      const float rr = __shfl_down(v.x, 1, 16);
      lm[j] = (wq == 0) ? 0.f : l;
      lp[j] = (wq == 15) ? 0.f : rr;
    }
    const float w00 = wl[ch * 9 + 0], w01 = wl[ch * 9 + 1], w02 = wl[ch * 9 + 2];
    const float w10 = wl[ch * 9 + 3], w11 = wl[ch * 9 + 4], w12 = wl[ch * 9 + 5];
    const float w20 = wl[ch * 9 + 6], w21 = wl[ch * 9 + 7], w22 = wl[ch * 9 + 8];
    const float bias = wl[576 + ch];
#pragma unroll
    for (int ro = 0; ro < 4; ++ro) {
      f32x4 acc = {bias, bias, bias, bias};
#pragma unroll
      for (int d = 0; d < 3; ++d) {
        const int j = ro + d;
        const float wa = (d == 0) ? w00 : (d == 1) ? w10 : w20;
        const float wb_ = (d == 0) ? w01 : (d == 1) ? w11 : w21;
        const float wc = (d == 0) ? w02 : (d == 1) ? w12 : w22;
        acc.x += wa * lm[j]   + wb_ * r[j].x + wc * r[j].y;
        acc.y += wa * r[j].x  + wb_ * r[j].y + wc * r[j].z;
        acc.z += wa * r[j].y  + wb_ * r[j].z + wc * r[j].w;
        acc.w += wa * r[j].z  + wb_ * r[j].w + wc * lp[j];
      }
      ushort4 o;
      o.x = f2h(acc.x); o.y = f2h(acc.y); o.z = f2h(acc.z); o.w = f2h(acc.w);
      *(ushort4*)&tile[ro][ch][wq * 4] = o;
    }
  }
  __syncthreads();

  const int icq = t & 15;
  const size_t outb = (size_t)b * 4096 * 1024 + (size_t)icb * 64 + icq * 4;
#pragma unroll
  for (int it = 0; it < 16; ++it) {
    const int ro = it >> 2;
    const int w = (it & 3) * 16 + (t >> 4);
    ushort4 o;
    o.x = tile[ro][icq * 4 + 0][w];
    o.y = tile[ro][icq * 4 + 1][w];
    o.z = tile[ro][icq * 4 + 2][w];
    o.w = tile[ro][icq * 4 + 3][w];
    const size_t p = (size_t)(h0 + ro) * 64 + w;
    *(ushort4*)(Tt + outb + p * 1024) = o;
  }
}

// ============================================================================
// K2: pointwise 1x1 as NT-GEMM, now with double-buffered LDS + counted vmcnt
// (T3/T4-lite): issue tile k+1's global_load_lds BEFORE waiting on tile k,
// wait with vmcnt(8) so the 8 prefetch loads stay in flight across the
// barrier. Schedule per iter: barrier-A (everyone done reading tile k-1, its
// buffer may be overwritten) -> issue k+1 -> vmcnt(8) -> barrier-B (tile k
// visible) -> MFMA. grid (n=32, m=6, b=16), 256 threads, 64 KB LDS.
// ============================================================================
__global__ __launch_bounds__(256) void pwgemm_kernel(
    const u16* __restrict__ W, const float* __restrict__ pwb,
    const u16* __restrict__ Tt, u16* __restrict__ FM) {
  __shared__ __align__(16) u16 sA[2][128 * 64];
  __shared__ __align__(16) u16 sB[2][128 * 64];
  const int b = blockIdx.z;
  const int m0 = blockIdx.y * 128, n0 = blockIdx.x * 128;
  const int t = threadIdx.x, wv = t >> 6, lane = t & 63;
  const int mw = (wv >> 1) * 64, nw = (wv & 1) * 64;
  const int l15 = lane & 15, lq = lane >> 4;
  const int rsw = (l15 & 7) << 3;           // read-side swizzle (row&7 == l15&7)
  f32x4 acc[4][4] = {};
  // pre-swizzled per-lane global source; wave-uniform LDS bases
  const int r8 = lane >> 3;                  // row-within-8 == (row&7)
  const int colsw = 8 * ((lane & 7) ^ r8);   // inverse-swizzled k-column
  const u16* gA = W + ((size_t)m0 + wv * 8 + r8) * 1024 + colsw;
  const u16* gB = Tt + ((size_t)b * 4096 + n0 + wv * 8 + r8) * 1024 + colsw;
  const int lofs = wv * 512;

  // prologue: issue tile 0 into buffer 0
#pragma unroll
  for (int jj = 0; jj < 4; ++jj) {
    g2l16(gA + (size_t)jj * 32 * 1024, &sA[0][lofs + jj * 2048]);
    g2l16(gB + (size_t)jj * 32 * 1024, &sB[0][lofs + jj * 2048]);
  }
  for (int kt = 0; kt < 16; ++kt) {
    const int cur = kt & 1;
    __builtin_amdgcn_s_barrier();          // A: tile kt-1 reads done everywhere
    if (kt < 15) {
      const int k1 = (kt + 1) * 64, nxt = cur ^ 1;
#pragma unroll
      for (int jj = 0; jj < 4; ++jj) {
        g2l16(gA + (size_t)jj * 32 * 1024 + k1, &sA[nxt][lofs + jj * 2048]);
        g2l16(gB + (size_t)jj * 32 * 1024 + k1, &sB[nxt][lofs + jj * 2048]);
      }
      asm volatile("s_waitcnt vmcnt(8)" ::: "memory");   // tile kt landed
    } else {
      asm volatile("s_waitcnt vmcnt(0)" ::: "memory");
    }
    __builtin_amdgcn_s_barrier();          // B: tile kt visible to all waves
    __builtin_amdgcn_sched_barrier(0);
#pragma unroll
    for (int ks = 0; ks < 2; ++ks) {
      s16x8 af[4], bfv[4];
      const int cbase = (ks * 32 + lq * 8) ^ rsw;
#pragma unroll
      for (int i = 0; i < 4; ++i)
        af[i] = *(const s16x8*)&sA[cur][(mw + i * 16 + l15) * 64 + cbase];
#pragma unroll
      for (int j = 0; j < 4; ++j)
        bfv[j] = *(const s16x8*)&sB[cur][(nw + j * 16 + l15) * 64 + cbase];
#pragma unroll
      for (int i = 0; i < 4; ++i)
#pragma unroll
        for (int j = 0; j < 4; ++j)
          acc[i][j] = MFMA(af[i], bfv[j], acc[i][j]);
    }
  }
#pragma unroll
  for (int i = 0; i < 4; ++i)
#pragma unroll
    for (int r = 0; r < 4; ++r) {
      const int oc = m0 + mw + i * 16 + lq * 4 + r;
      const float bias = pwb[oc];
#pragma unroll
      for (int j = 0; j < 4; ++j) {
        const int p = n0 + nw + j * 16 + l15;
        FM[((size_t)b * 768 + oc) * 4096 + p] = f2h(acc[i][j][r] + bias);
      }
    }
}

// ============================================================================
// K3: attention per (b, h, strip of 64 Q rows). Waves split S by ROWS ->
// softmax fully wave-local. Block-id XCD swizzle: default round-robin puts
// the 4 strips of one (b,h) on 4 DIFFERENT XCDs, so K/V (64 KB, shared by
// the 4 strips) is fetched 4x. Bijective chunked remap lg=(lin&7)*512+lin>>3
// makes strips of one (b,h) adjacent on the SAME XCD -> K/V L2-hit.
// grid (4,64,16) linearized, 256 threads.
// ============================================================================
__global__ __launch_bounds__(256) void attn_kernel(
    const u16* __restrict__ FM, float* __restrict__ out) {
  __shared__ __align__(16) u16 sKV[16384];  // K[256][64]; later VT[64][256]
  __shared__ __align__(16) u16 sP[16384];   // P[64][256]
  const int lin = blockIdx.x + 4 * (blockIdx.y + 64 * blockIdx.z);
  const int lg = (lin & 7) * 512 + (lin >> 3);   // bijective XCD-chunk remap
  const int sb = lg & 3, h = (lg >> 2) & 63, b = lg >> 8;
  const int t = threadIdx.x, wv = t >> 6, lane = t & 63;
  const int l15 = lane & 15, lq = lane >> 4;
  const int rsw = (l15 & 7) << 3;           // read-side swizzle (K, P tiles)
  const u16* fmb = FM + (size_t)b * 768 * 4096;
  const int hofs = h * 64;

  // stage K[256][64] (channels 256..511) via global_load_lds, swizzled layout
  const int r8 = lane >> 3;
  const int colsw = 8 * ((lane & 7) ^ r8);
  const u16* gK = fmb + ((size_t)(256 + wv * 8 + r8)) * 4096 + hofs + colsw;
  u16* lK = sKV + wv * 512;
#pragma unroll
  for (int it = 0; it < 8; ++it)
    g2l16(gK + (size_t)it * 32 * 4096, lK + it * 2048);

  // Q fragments for this wave's 16 rows (A layout: m=l15, k contiguous)
  const int qrow = sb * 64 + wv * 16 + l15;
  s16x8 qf[2];
#pragma unroll
  for (int ks = 0; ks < 2; ++ks)
    qf[ks] = *(const s16x8*)(fmb + (size_t)qrow * 4096 + hofs + ks * 32 + lq * 8);
  __syncthreads();   // vmcnt(0) drained before barrier: K tile visible

  // S[m][d]: m in wave's 16 rows, d = 0..255 across 16 j-blocks
  f32x4 sreg[16] = {};
#pragma unroll
  for (int ks = 0; ks < 2; ++ks) {
    const int cbase = (ks * 32 + lq * 8) ^ rsw;
#pragma unroll
    for (int j = 0; j < 16; ++j) {
      const s16x8 kf = *(const s16x8*)&sKV[(j * 16 + l15) * 64 + cbase];
      sreg[j] = MFMA(qf[ks], kf, sreg[j]);
    }
  }

  // wave-local softmax over d. Row m_local = lq*4 + r; cols = j*16 + l15.
  float inv[4], mx[4];
#pragma unroll
  for (int r = 0; r < 4; ++r) {
    float v = -3.4e38f;
#pragma unroll
    for (int j = 0; j < 16; ++j) v = fmaxf(v, sreg[j][r]);
#pragma unroll
    for (int mk = 1; mk < 16; mk <<= 1) v = fmaxf(v, __shfl_xor(v, mk, 64));
    mx[r] = v;
  }
#pragma unroll
  for (int r = 0; r < 4; ++r) {
    float ss = 0.f;
#pragma unroll
    for (int j = 0; j < 16; ++j) {
      const float e = __expf(fminf(sreg[j][r] - mx[r], 0.f));
      sreg[j][r] = e;
      ss += e;
    }
#pragma unroll
    for (int mk = 1; mk < 16; mk <<= 1) ss += __shfl_xor(ss, mk, 64);
    inv[r] = 1.0f / fmaxf(ss, 1e-30f);
  }
  // P -> sP[row][col ^ ((row&7)<<3)]
#pragma unroll
  for (int r = 0; r < 4; ++r) {
    const int row = wv * 16 + lq * 4 + r;
    const int s = (row & 7) << 3;
#pragma unroll
    for (int j = 0; j < 16; ++j)
      sP[row * 256 + ((j * 16 + l15) ^ s)] = f2h(sreg[j][r] * inv[r]);
  }
  __syncthreads();   // all QK reads of sKV done; P visible

  // stage V^T into sKV: VT[w][d] (channels 512..767), write/read-balanced swz
#pragma unroll
  for (int it = 0; it < 8; ++it) {
    const int c = it * 256 + t;
    const int d = c >> 3, w0 = (c & 7) * 8;
    const s16x8 vv = *(const s16x8*)(fmb + (size_t)(512 + d) * 4096 + hofs + w0);
#pragma unroll
    for (int j = 0; j < 8; ++j) {
      const int rr = w0 + j;
      const int s = ((rr & 7) ^ ((rr >> 3) & 7)) << 3;
      sKV[rr * 256 + (d ^ s)] = (u16)vv[j];
    }
  }
  __syncthreads();

  // O[m][w] = sum_d P[m][d] V[d][w]; wave's 16 rows, full K=256
  f32x4 o[4] = {};
#pragma unroll
  for (int kk = 0; kk < 8; ++kk) {
    const int cbase = kk * 32 + lq * 8;
    const s16x8 pf = *(const s16x8*)&sP[(wv * 16 + l15) * 256 + (cbase ^ rsw)];
#pragma unroll
    for (int j = 0; j < 4; ++j) {
      const int rr = j * 16 + l15;
      const int vsw = ((rr & 7) ^ ((rr >> 3) & 7)) << 3;
      const s16x8 vf = *(const s16x8*)&sKV[rr * 256 + (cbase ^ vsw)];
      o[j] = MFMA(pf, vf, o[j]);
    }
  }
  // out flat = [b][h][c][w], fp32
  const size_t ob = (((size_t)b * 64 + h) * 256 + sb * 64 + wv * 16) * 64;
#pragma unroll
  for (int j = 0; j < 4; ++j)
#pragma unroll
    for (int r = 0; r < 4; ++r)
      out[ob + (size_t)(lq * 4 + r) * 64 + j * 16 + l15] = o[j][r];
}

extern "C" void kernel_launch(void* const* d_in, const int* in_sizes, int n_in,
                              void* d_out, int out_size, void* d_ws, size_t ws_size,
                              hipStream_t stream) {
  (void)in_sizes; (void)n_in; (void)out_size; (void)ws_size;
  const float* x   = (const float*)d_in[0];
  const float* y   = (const float*)d_in[1];
  const float* dww = (const float*)d_in[2];
  const float* dwb = (const float*)d_in[3];
  const float* pww = (const float*)d_in[4];
  const float* pwb = (const float*)d_in[5];
  u16* Tt   = (u16*)d_ws;                        // [16][4096][1024] f16 = 128 MiB
  u16* FM   = Tt + (size_t)16 * 4096 * 1024;     // [16][768][4096]  f16 =  96 MiB
  u16* Wb16 = FM + (size_t)16 * 768 * 4096;      // [768][1024]      f16 = 1.5 MiB
  float* out = (float*)d_out;

  convw_kernel<<<dim3(768), 256, 0, stream>>>(pww, Wb16);
  dwconv_kernel<<<dim3(16, 16, 16), 256, 0, stream>>>(x, y, dww, dwb, Tt);
  pwgemm_kernel<<<dim3(32, 6, 16), 256, 0, stream>>>(Wb16, pwb, Tt, FM);
  attn_kernel<<<dim3(4, 64, 16), 256, 0, stream>>>(FM, out);
}